// Round 3
// baseline (2643.219 us; speedup 1.0000x reference)
//
#include <hip/hip_runtime.h>
#include <math.h>

#define BATCH 10
#define HID 128
#define OUT 7
#define MAXLEN 2048
#define NT 512
#define RINGD 512
#define OFF_STATE ((size_t)BATCH * MAXLEN * OUT)

typedef float float2v __attribute__((ext_vector_type(2)));
typedef float float4v __attribute__((ext_vector_type(4)));

__device__ __forceinline__ float sigm_(float x) { return 1.0f / (1.0f + __expf(-x)); }
__device__ __forceinline__ float tanh_(float x) { return 1.0f - 2.0f / (1.0f + __expf(2.0f * x)); }

__device__ __forceinline__ float2v vlo(float4v v) { return __builtin_shufflevector(v, v, 0, 1); }
__device__ __forceinline__ float2v vhi(float4v v) { return __builtin_shufflevector(v, v, 2, 3); }

// Butterfly sum over a 4-lane group (lanes quad-aligned): 2 DPP rounds,
// every lane ends with the group total. Pure VALU, hazards handled by compiler.
__device__ __forceinline__ float grp4_sum(float v) {
    v += __int_as_float(__builtin_amdgcn_update_dpp(0, __float_as_int(v), 0xB1, 0xF, 0xF, true)); // xor1
    v += __int_as_float(__builtin_amdgcn_update_dpp(0, __float_as_int(v), 0x4E, 0xF, 0xF, true)); // xor2
    return v;
}

__global__
__attribute__((amdgpu_flat_work_group_size(NT, NT), amdgpu_waves_per_eu(2, 2)))
void decoder_rnn_kernel(const float* __restrict__ h0,
                        const float* __restrict__ c0,
                        const float* __restrict__ tonehot,   // (MAXLEN+1, 1, OUT)
                        const void*  __restrict__ tf_raw,    // bool mask, int8 or int32
                        const float* __restrict__ Wih,       // (4H, OUT)
                        const float* __restrict__ Whh,       // (4H, H)
                        const float* __restrict__ bih,
                        const float* __restrict__ bhh,
                        const float* __restrict__ Wout,      // (OUT, H)
                        const float* __restrict__ bout,
                        float* __restrict__ out)
{
    // R19: owner-computes layout. Lane (wv, grp=lane>>2, ksl=lane&3) owns
    // h element j=wv*16+grp; computes all 4 gate rows {q*128+j} over K slice
    // [ksl*32, ksl*32+32). 2-round quad butterfly -> lane-local pointwise.
    // ONE barrier/step (h double-buffered). wih_eff in 28 regs/lane, selected
    // by cndmask chain (no post-argmax LDS latency).
    __shared__ __align__(16) float h_lds[2][HID];    // double-buffered h
    __shared__ float ring[RINGD][OUT];               // RAW logits (bout at flush)
    __shared__ unsigned char tgt8[MAXLEN];
    __shared__ unsigned char tf8[MAXLEN];
    __shared__ int tf_byte_mode;

    const int t    = threadIdx.x;
    const int lane = t & 63;
    const int wv   = t >> 6;          // 0..7
    const int ksl  = lane & 3;        // K slice (32 wide)
    const int grp  = lane >> 2;       // 0..15: h element within wave's slice
    const int b    = blockIdx.x;
    const int j    = wv * 16 + grp;   // owned h element

    // ---- persistent W_hh: 4 gate rows x 32 K per lane (128 VGPR), pinned ----
    // chunk order rotated by 2*ksl so the 4 group-addresses per ds_read_b128
    // land on distinct bank quads (conflict-free 16-way broadcast).
    float4v wgt[4][8];
    #pragma unroll
    for (int q = 0; q < 4; q++)
        #pragma unroll
        for (int m = 0; m < 8; m++) {
            const int kb = ksl * 32 + (((m + 2 * ksl) & 7) << 2);
            wgt[q][m] = *(const float4v*)&Whh[(size_t)(q * HID + j) * HID + kb];
        }
    #pragma unroll
    for (int q = 0; q < 4; q++)
        #pragma unroll
        for (int m = 0; m < 8; m++)
            asm volatile("" : "+v"(wgt[q][m]));   // forbid demotion/remat

    // logit weights: lane group grp -> logit row grp (zeros for grp>=7; all
    // waves compute logits redundantly so xsel needs no cross-wave hop)
    float4v lwv[8];
    #pragma unroll
    for (int m = 0; m < 8; m++) { float4v z = {0.f, 0.f, 0.f, 0.f}; lwv[m] = z; }
    if (grp < OUT) {
        #pragma unroll
        for (int m = 0; m < 8; m++) {
            const int kb = ksl * 32 + (((m + 2 * ksl) & 7) << 2);
            lwv[m] = *(const float4v*)&Wout[(size_t)grp * HID + kb];
        }
    }

    // wih_eff in registers: [x][q] for my j (28 regs)
    float wihr[OUT][4];
    #pragma unroll
    for (int x = 0; x < OUT; x++)
        #pragma unroll
        for (int q = 0; q < 4; q++) {
            const int g = q * HID + j;
            wihr[x][q] = Wih[(size_t)g * OUT + x] + bih[g] + bhh[g];
        }

    float boutr[OUT];
    #pragma unroll
    for (int jj = 0; jj < OUT; jj++) boutr[jj] = bout[jj];

    // ---- LDS setup ----
    if (t == 0) tf_byte_mode = 0;
    for (int s = t; s < MAXLEN; s += NT) {
        const float* row = tonehot + (size_t)(s + 1) * OUT;
        int idx = 0;
        #pragma unroll
        for (int jj = 0; jj < OUT; jj++) if (row[jj] > 0.5f) idx = jj;
        tgt8[s] = (unsigned char)idx;
    }
    __syncthreads();
    {   // tf_mask layout detection (int8 bool vs int32) — proven R1-R16
        const unsigned char* tb = (const unsigned char*)tf_raw;
        int mis = 0;
        for (int p = t; p < MAXLEN; p += NT)
            if ((p & 3) && tb[p]) mis = 1;
        if (mis) atomicOr(&tf_byte_mode, 1);
    }
    // ---- state init ----
    float c_reg = c0[b * HID + j];
    float hv    = h0[b * HID + j];
    if (t < HID) h_lds[0][t] = h0[b * HID + t];
    __syncthreads();
    if (tf_byte_mode) {
        const unsigned char* tb = (const unsigned char*)tf_raw;
        for (int s = t; s < MAXLEN; s += NT) tf8[s] = (tb[s] != 0);
    } else {
        const int* ti = (const int*)tf_raw;
        for (int s = t; s < MAXLEN; s += NT) tf8[s] = (ti[s] != 0);
    }
    __syncthreads();

    float* outlp = out + (size_t)b * MAXLEN * OUT;

    for (int s = 0; s < MAXLEN; s++) {
        const float* hb = h_lds[s & 1];
        float*       hw = h_lds[(s & 1) ^ 1];

        // uniform step data, issue early (hidden under FMA block)
        int tfp = 0, tgp = 0;
        if (s > 0) { tfp = tf8[s - 1]; tgp = tgt8[s - 1]; }

        // ---- matvec: 4 gates + logit row, packed fp32 FMA ----
        float2v acc0 = {0.f,0.f}, acc1 = {0.f,0.f}, acc2 = {0.f,0.f},
                acc3 = {0.f,0.f}, accl = {0.f,0.f};
        #pragma unroll
        for (int m = 0; m < 8; m++) {
            const int kb = ksl * 32 + (((m + 2 * ksl) & 7) << 2);
            const float4v h4  = *(const float4v*)&hb[kb];
            const float2v hlo = vlo(h4), hhi = vhi(h4);
            acc0 = __builtin_elementwise_fma(vlo(wgt[0][m]), hlo, acc0);
            acc0 = __builtin_elementwise_fma(vhi(wgt[0][m]), hhi, acc0);
            acc1 = __builtin_elementwise_fma(vlo(wgt[1][m]), hlo, acc1);
            acc1 = __builtin_elementwise_fma(vhi(wgt[1][m]), hhi, acc1);
            acc2 = __builtin_elementwise_fma(vlo(wgt[2][m]), hlo, acc2);
            acc2 = __builtin_elementwise_fma(vhi(wgt[2][m]), hhi, acc2);
            acc3 = __builtin_elementwise_fma(vlo(wgt[3][m]), hlo, acc3);
            acc3 = __builtin_elementwise_fma(vhi(wgt[3][m]), hhi, acc3);
            accl = __builtin_elementwise_fma(vlo(lwv[m]),    hlo, accl);
            accl = __builtin_elementwise_fma(vhi(lwv[m]),    hhi, accl);
        }
        const float a0 = grp4_sum(acc0[0] + acc0[1]);
        const float a1 = grp4_sum(acc1[0] + acc1[1]);
        const float a2 = grp4_sum(acc2[0] + acc2[1]);
        const float a3 = grp4_sum(acc3[0] + acc3[1]);
        const float al = grp4_sum(accl[0] + accl[1]);

        // ---- xsel: ring-write logits(s-1); argmax only on non-TF steps ----
        int xsel = OUT - 1;
        if (s > 0) {
            if (wv == 0 && ksl == 0 && grp < OUT)
                ring[(s - 1) & (RINGD - 1)][grp] = al;
            if (tfp) {
                xsel = tgp;
            } else {
                float lg[OUT];
                #pragma unroll
                for (int jj = 0; jj < OUT; jj++)
                    lg[jj] = __int_as_float(__builtin_amdgcn_readlane(__float_as_int(al), 4 * jj)) + boutr[jj];
                float bv = lg[0]; int bi = 0;
                #pragma unroll
                for (int jj = 1; jj < OUT; jj++) if (lg[jj] > bv) { bv = lg[jj]; bi = jj; }
                xsel = bi;
            }
        }

        // ---- wih column select from registers (no LDS latency) ----
        float w0 = wihr[0][0], w1 = wihr[0][1], w2 = wihr[0][2], w3 = wihr[0][3];
        #pragma unroll
        for (int x = 1; x < OUT; x++) {
            const bool px = (xsel == x);
            w0 = px ? wihr[x][0] : w0;
            w1 = px ? wihr[x][1] : w1;
            w2 = px ? wihr[x][2] : w2;
            w3 = px ? wihr[x][3] : w3;
        }

        // ---- lane-local pointwise (4-way redundant within quad) ----
        const float ri = a0 + w0, rf = a1 + w1, rg = a2 + w2, ro = a3 + w3;
        const float cn = sigm_(rf) * c_reg + sigm_(ri) * tanh_(rg);
        c_reg = cn;
        hv = sigm_(ro) * tanh_(cn);
        if (ksl == 0) hw[j] = hv;

        // ---- deferred log-softmax flush (waves 0-3, 8x per run) ----
        if (t < 256 && (s & 255) == 1 && s > 256) {
            const int step = (s - 257) + t;          // slot-disjoint from (s-1)
            const int slot = step & (RINGD - 1);
            float v[OUT];
            #pragma unroll
            for (int jj = 0; jj < OUT; jj++) v[jj] = ring[slot][jj] + boutr[jj];
            float mx = v[0];
            #pragma unroll
            for (int jj = 1; jj < OUT; jj++) mx = fmaxf(mx, v[jj]);
            float sum = 0.f;
            #pragma unroll
            for (int jj = 0; jj < OUT; jj++) sum += __expf(v[jj] - mx);
            const float lse = mx + __logf(sum);
            float* dst = outlp + (size_t)step * OUT;
            #pragma unroll
            for (int jj = 0; jj < OUT; jj++) dst[jj] = v[jj] - lse;
        }
        __syncthreads();   // single barrier: h(s+1) published, old buffer free
    }

    // ---- epilogue: raw logits for step 2047 from final h (in buffer 0) ----
    {
        float2v accl = {0.f, 0.f};
        #pragma unroll
        for (int m = 0; m < 8; m++) {
            const int kb = ksl * 32 + (((m + 2 * ksl) & 7) << 2);
            const float4v h4 = *(const float4v*)&h_lds[0][kb];
            accl = __builtin_elementwise_fma(vlo(lwv[m]), vlo(h4), accl);
            accl = __builtin_elementwise_fma(vhi(lwv[m]), vhi(h4), accl);
        }
        const float al = grp4_sum(accl[0] + accl[1]);
        if (wv == 0 && ksl == 0 && grp < OUT)
            ring[(MAXLEN - 1) & (RINGD - 1)][grp] = al;
    }
    __syncthreads();
    if (t < 256) {   // final flush: steps 1792..2047
        const int step = (MAXLEN - 256) + t;
        const int slot = step & (RINGD - 1);
        float v[OUT];
        #pragma unroll
        for (int jj = 0; jj < OUT; jj++) v[jj] = ring[slot][jj] + boutr[jj];
        float mx = v[0];
        #pragma unroll
        for (int jj = 1; jj < OUT; jj++) mx = fmaxf(mx, v[jj]);
        float sum = 0.f;
        #pragma unroll
        for (int jj = 0; jj < OUT; jj++) sum += __expf(v[jj] - mx);
        const float lse = mx + __logf(sum);
        float* dst = outlp + (size_t)step * OUT;
        #pragma unroll
        for (int jj = 0; jj < OUT; jj++) dst[jj] = v[jj] - lse;
    }
    if (ksl == 0) {
        out[OFF_STATE + b * HID + j] = hv;                        // hT
        out[OFF_STATE + BATCH * HID + b * HID + j] = c_reg;       // cT
    }
}

extern "C" void kernel_launch(void* const* d_in, const int* in_sizes, int n_in,
                              void* d_out, int out_size, void* d_ws, size_t ws_size,
                              hipStream_t stream) {
    const float* h0    = (const float*)d_in[0];
    const float* c0    = (const float*)d_in[1];
    const float* toh   = (const float*)d_in[2];
    const void*  tfm   = (const void*) d_in[3];
    const float* Wih   = (const float*)d_in[4];
    const float* Whh   = (const float*)d_in[5];
    const float* bih   = (const float*)d_in[6];
    const float* bhh   = (const float*)d_in[7];
    const float* Wout  = (const float*)d_in[8];
    const float* bout  = (const float*)d_in[9];
    float* out = (float*)d_out;

    decoder_rnn_kernel<<<dim3(BATCH), dim3(NT), 0, stream>>>(
        h0, c0, toh, tfm, Wih, Whh, bih, bhh, Wout, bout, out);
}

// Round 4
// 2407.214 us; speedup vs baseline: 1.0980x; 1.0980x over previous
//
#include <hip/hip_runtime.h>
#include <math.h>

#define BATCH 10
#define HID 128
#define OUT 7
#define MAXLEN 2048
#define NT 1024
#define RINGD 512
#define OFF_STATE ((size_t)BATCH * MAXLEN * OUT)

typedef float float2v __attribute__((ext_vector_type(2)));
typedef float float4v __attribute__((ext_vector_type(4)));

__device__ __forceinline__ float sigm_(float x) { return 1.0f / (1.0f + __expf(-x)); }
__device__ __forceinline__ float tanh_(float x) { return 1.0f - 2.0f / (1.0f + __expf(2.0f * x)); }

__device__ __forceinline__ float2v vlo(float4v v) { return __builtin_shufflevector(v, v, 0, 1); }
__device__ __forceinline__ float2v vhi(float4v v) { return __builtin_shufflevector(v, v, 2, 3); }

// guaranteed packed fp32 FMA (2 MACs/instr)
__device__ __forceinline__ void pk_fma(float2v& acc, float2v w, float2v h) {
    asm("v_pk_fma_f32 %0, %1, %2, %0" : "+v"(acc) : "v"(w), "v"(h));
}

// 2-round butterfly: every lane of each 4-group holds the 4-lane sum.
__device__ __forceinline__ float quad_sum(float v) {
    v += __int_as_float(__builtin_amdgcn_update_dpp(0, __float_as_int(v), 0xB1, 0xF, 0xF, true)); // xor1
    v += __int_as_float(__builtin_amdgcn_update_dpp(0, __float_as_int(v), 0x4E, 0xF, 0xF, true)); // xor2
    return v;
}
// 3-round butterfly over 8-lane group (quad-uniform before mirror -> xor4 ok)
__device__ __forceinline__ float grp8_sum(float v) {
    v += __int_as_float(__builtin_amdgcn_update_dpp(0, __float_as_int(v), 0xB1, 0xF, 0xF, true));
    v += __int_as_float(__builtin_amdgcn_update_dpp(0, __float_as_int(v), 0x4E, 0xF, 0xF, true));
    v += __int_as_float(__builtin_amdgcn_update_dpp(0, __float_as_int(v), 0x141, 0xF, 0xF, true));
    return v;
}

__global__
__attribute__((amdgpu_flat_work_group_size(NT, NT), amdgpu_waves_per_eu(4, 4)))
void decoder_rnn_kernel(const float* __restrict__ h0,
                        const float* __restrict__ c0,
                        const float* __restrict__ tonehot,   // (MAXLEN+1, 1, OUT)
                        const void*  __restrict__ tf_raw,    // bool mask, int8 or int32
                        const float* __restrict__ Wih,       // (4H, OUT)
                        const float* __restrict__ Whh,       // (4H, H)
                        const float* __restrict__ bih,
                        const float* __restrict__ bhh,
                        const float* __restrict__ Wout,      // (OUT, H)
                        const float* __restrict__ bout,
                        float* __restrict__ out)
{
    // R20: 16 waves; wave w owns gates [(w>>1)*64,+64) over K-half (w&1)*64.
    // Lane: 8 gates x 8 K = 64 weight floats (16 quads) -> register-resident.
    // asm v_pk_fma_f32; 2-round DPP + 4 partial planes; argmax in phase2a
    // (greedy steps only); logits via LDS-staged Wout on waves 0/1.
    __shared__ __align__(16) float h_lds[HID];
    __shared__ __align__(16) float gpart[4][520];    // partial planes, padded
    __shared__ float wih_eff[OUT * 512];             // Wih^T + bias, [x][g]
    __shared__ float WoutL[8][132];                  // row 7 = zeros, padded
    __shared__ float lp[2][8];                       // logit K-half partials
    __shared__ float ring[RINGD][OUT];               // RAW logits
    __shared__ unsigned char tgt8[MAXLEN];
    __shared__ unsigned char tf8[MAXLEN];
    __shared__ int tf_byte_mode;

    const int t     = threadIdx.x;
    const int lane  = t & 63;
    const int wv    = t >> 6;         // 0..15
    const int ksl   = lane & 7;       // K sub-slice (8 wide)
    const int grp   = lane >> 3;      // 8-gate group
    const int b     = blockIdx.x;
    const int kset  = wv & 1;         // K-half
    const int gw    = wv >> 1;        // gate block
    const int gbase = gw * 64 + grp * 8;
    const int kb    = kset * 64 + ksl * 8;

    // ---- persistent W_hh: 8 gates x 8 K = 16 quads (64 VGPR) ----
    float4v wq[8][2];
    #pragma unroll
    for (int g = 0; g < 8; g++)
        #pragma unroll
        for (int p = 0; p < 2; p++)
            wq[g][p] = *(const float4v*)&Whh[(size_t)(gbase + g) * HID + kb + p * 4];

    float boutr[OUT];
    #pragma unroll
    for (int j = 0; j < OUT; j++) boutr[j] = bout[j];

    // ---- LDS setup ----
    for (int idx = t; idx < OUT * 512; idx += NT) {
        int x = idx >> 9, g = idx & 511;
        wih_eff[idx] = Wih[g * OUT + x] + bih[g] + bhh[g];
    }
    if (t < HID) WoutL[7][t] = 0.f;                 // zero pad row
    for (int idx = t; idx < OUT * HID; idx += NT)
        WoutL[idx >> 7][idx & 127] = Wout[idx];
    if (t == 0) tf_byte_mode = 0;
    for (int s = t; s < MAXLEN; s += NT) {
        const float* row = tonehot + (size_t)(s + 1) * OUT;
        int idx = 0;
        #pragma unroll
        for (int j = 0; j < OUT; j++) if (row[j] > 0.5f) idx = j;
        tgt8[s] = (unsigned char)idx;
    }
    __syncthreads();
    {   // tf_mask layout detection (int8 bool vs int32) — proven R1-R16
        const unsigned char* tb = (const unsigned char*)tf_raw;
        int mis = 0;
        for (int p = t; p < MAXLEN; p += NT)
            if ((p & 3) && tb[p]) mis = 1;
        if (mis) atomicOr(&tf_byte_mode, 1);
    }
    // ---- state init ----
    float c_reg = 0.f, hv = 0.f;
    if (t < HID) {
        hv    = h0[b * HID + t];
        c_reg = c0[b * HID + t];
        h_lds[t] = hv;
    }
    __syncthreads();
    if (tf_byte_mode) {
        const unsigned char* tb = (const unsigned char*)tf_raw;
        for (int s = t; s < MAXLEN; s += NT) tf8[s] = (tb[s] != 0);
    } else {
        const int* ti = (const int*)tf_raw;
        for (int s = t; s < MAXLEN; s += NT) tf8[s] = (ti[s] != 0);
    }
    __syncthreads();

    float* outlp = out + (size_t)b * MAXLEN * OUT;

    for (int s = 0; s < MAXLEN; s++) {
        // ---- phase 1: gates matvec (pk_fma) + logit K-halves on waves 0/1 ----
        const float4v h0q = *(const float4v*)&h_lds[kb];
        const float4v h1q = *(const float4v*)&h_lds[kb + 4];
        const float2v hl0 = vlo(h0q), hh0 = vhi(h0q);
        const float2v hl1 = vlo(h1q), hh1 = vhi(h1q);

        float2v acc[8];
        #pragma unroll
        for (int g = 0; g < 8; g++) { float2v z = {0.f, 0.f}; acc[g] = z; }
        #pragma unroll
        for (int g = 0; g < 8; g++) {
            pk_fma(acc[g], vlo(wq[g][0]), hl0);
            pk_fma(acc[g], vhi(wq[g][0]), hh0);
            pk_fma(acc[g], vlo(wq[g][1]), hl1);
            pk_fma(acc[g], vhi(wq[g][1]), hh1);
        }
        float a[8];
        #pragma unroll
        for (int g = 0; g < 8; g++) a[g] = quad_sum(acc[g][0] + acc[g][1]);
        if ((ksl & 3) == 0) {
            const int pl = (kset << 1) | (ksl >> 2);
            float4v g4a, g4b;
            g4a[0] = a[0]; g4a[1] = a[1]; g4a[2] = a[2]; g4a[3] = a[3];
            g4b[0] = a[4]; g4b[1] = a[5]; g4b[2] = a[6]; g4b[3] = a[7];
            *(float4v*)&gpart[pl][gbase]     = g4a;
            *(float4v*)&gpart[pl][gbase + 4] = g4b;
        }
        if (wv < 2) {   // logit row grp over my K-half (row 7 reads zeros)
            const float4v wo0 = *(const float4v*)&WoutL[grp][kb];
            const float4v wo1 = *(const float4v*)&WoutL[grp][kb + 4];
            float2v la = {0.f, 0.f};
            pk_fma(la, vlo(wo0), hl0);
            pk_fma(la, vhi(wo0), hh0);
            pk_fma(la, vlo(wo1), hl1);
            pk_fma(la, vhi(wo1), hh1);
            const float al = grp8_sum(la[0] + la[1]);
            if (ksl == 0 && grp < OUT) lp[wv][grp] = al;
        }
        __syncthreads();   // A: gpart + lp ready; h_lds reads done

        // ---- phase 2a: pointwise (waves 0,1) ----
        if (t < HID) {
            const float ps0 = (gpart[0][t] + gpart[1][t]) + (gpart[2][t] + gpart[3][t]);
            const float ps1 = (gpart[0][128 + t] + gpart[1][128 + t]) + (gpart[2][128 + t] + gpart[3][128 + t]);
            const float ps2 = (gpart[0][256 + t] + gpart[1][256 + t]) + (gpart[2][256 + t] + gpart[3][256 + t]);
            const float ps3 = (gpart[0][384 + t] + gpart[1][384 + t]) + (gpart[2][384 + t] + gpart[3][384 + t]);
            int xsel = OUT - 1;
            if (s > 0) {
                const int tfp = tf8[s - 1];
                if (t < OUT) ring[(s - 1) & (RINGD - 1)][t] = lp[0][t] + lp[1][t];
                if (tfp) {
                    xsel = tgt8[s - 1];
                } else {
                    float lg[OUT];
                    #pragma unroll
                    for (int j = 0; j < OUT; j++)
                        lg[j] = lp[0][j] + lp[1][j] + boutr[j];
                    float bv = lg[0]; int bi = 0;
                    #pragma unroll
                    for (int j = 1; j < OUT; j++) if (lg[j] > bv) { bv = lg[j]; bi = j; }
                    xsel = bi;
                }
            }
            const int xo = xsel * 512;
            const float ri = ps0 + wih_eff[xo + t];
            const float rf = ps1 + wih_eff[xo + 128 + t];
            const float rg = ps2 + wih_eff[xo + 256 + t];
            const float ro = ps3 + wih_eff[xo + 384 + t];
            const float cn = sigm_(rf) * c_reg + sigm_(ri) * tanh_(rg);
            c_reg = cn;
            hv = sigm_(ro) * tanh_(cn);
            h_lds[t] = hv;
        } else if (t >= 128 && t < 384 && (s & 255) == 1 && s > 256) {
            // ---- phase 2b: deferred log-softmax flush (waves 2-5) ----
            const int step = (s - 257) + (t - 128);      // slot-disjoint from (s-1)
            const int slot = step & (RINGD - 1);
            float v[OUT];
            #pragma unroll
            for (int j = 0; j < OUT; j++) v[j] = ring[slot][j] + boutr[j];
            float mx = v[0];
            #pragma unroll
            for (int j = 1; j < OUT; j++) mx = fmaxf(mx, v[j]);
            float sum = 0.f;
            #pragma unroll
            for (int j = 0; j < OUT; j++) sum += __expf(v[j] - mx);
            const float lse = mx + __logf(sum);
            float* dst = outlp + (size_t)step * OUT;
            #pragma unroll
            for (int j = 0; j < OUT; j++) dst[j] = v[j] - lse;
        }
        __syncthreads();   // C: h(s+1) visible to all waves
    }

    // ---- epilogue: raw logits for step 2047 from final h ----
    if (wv < 2) {
        const float4v h0q = *(const float4v*)&h_lds[kb];
        const float4v h1q = *(const float4v*)&h_lds[kb + 4];
        const float4v wo0 = *(const float4v*)&WoutL[grp][kb];
        const float4v wo1 = *(const float4v*)&WoutL[grp][kb + 4];
        float2v la = {0.f, 0.f};
        pk_fma(la, vlo(wo0), vlo(h0q));
        pk_fma(la, vhi(wo0), vhi(h0q));
        pk_fma(la, vlo(wo1), vlo(h1q));
        pk_fma(la, vhi(wo1), vhi(h1q));
        const float al = grp8_sum(la[0] + la[1]);
        if (ksl == 0 && grp < OUT) lp[wv][grp] = al;
    }
    __syncthreads();
    if (t < OUT)
        ring[(MAXLEN - 1) & (RINGD - 1)][t] = lp[0][t] + lp[1][t];
    __syncthreads();
    if (t < 256) {   // final flush: steps 1792..2047
        const int step = (MAXLEN - 256) + t;
        const int slot = step & (RINGD - 1);
        float v[OUT];
        #pragma unroll
        for (int j = 0; j < OUT; j++) v[j] = ring[slot][j] + boutr[j];
        float mx = v[0];
        #pragma unroll
        for (int j = 1; j < OUT; j++) mx = fmaxf(mx, v[j]);
        float sum = 0.f;
        #pragma unroll
        for (int j = 0; j < OUT; j++) sum += __expf(v[j] - mx);
        const float lse = mx + __logf(sum);
        float* dst = outlp + (size_t)step * OUT;
        #pragma unroll
        for (int j = 0; j < OUT; j++) dst[j] = v[j] - lse;
    }
    if (t < HID) {
        out[OFF_STATE + b * HID + t] = hv;                        // hT
        out[OFF_STATE + BATCH * HID + b * HID + t] = c_reg;       // cT
    }
}

extern "C" void kernel_launch(void* const* d_in, const int* in_sizes, int n_in,
                              void* d_out, int out_size, void* d_ws, size_t ws_size,
                              hipStream_t stream) {
    const float* h0    = (const float*)d_in[0];
    const float* c0    = (const float*)d_in[1];
    const float* toh   = (const float*)d_in[2];
    const void*  tfm   = (const void*) d_in[3];
    const float* Wih   = (const float*)d_in[4];
    const float* Whh   = (const float*)d_in[5];
    const float* bih   = (const float*)d_in[6];
    const float* bhh   = (const float*)d_in[7];
    const float* Wout  = (const float*)d_in[8];
    const float* bout  = (const float*)d_in[9];
    float* out = (float*)d_out;

    decoder_rnn_kernel<<<dim3(BATCH), dim3(NT), 0, stream>>>(
        h0, c0, toh, tfm, Wih, Whh, bih, bhh, Wout, bout, out);
}

// Round 5
// 2300.062 us; speedup vs baseline: 1.1492x; 1.0466x over previous
//
#include <hip/hip_runtime.h>
#include <math.h>

#define BATCH 10
#define HID 128
#define OUT 7
#define MAXLEN 2048
#define NT 1024
#define RINGD 512
#define OFF_STATE ((size_t)BATCH * MAXLEN * OUT)

typedef float float2v __attribute__((ext_vector_type(2)));
typedef float float4v __attribute__((ext_vector_type(4)));

__device__ __forceinline__ float sigm_(float x) { return 1.0f / (1.0f + __expf(-x)); }
__device__ __forceinline__ float tanh_(float x) { return 1.0f - 2.0f / (1.0f + __expf(2.0f * x)); }

__device__ __forceinline__ float2v vlo(float4v v) { return __builtin_shufflevector(v, v, 0, 1); }
__device__ __forceinline__ float2v vhi(float4v v) { return __builtin_shufflevector(v, v, 2, 3); }

// guaranteed packed fp32 FMA (2 MACs/instr)
__device__ __forceinline__ void pk_fma(float2v& acc, float2v w, float2v h) {
    asm("v_pk_fma_f32 %0, %1, %2, %0" : "+v"(acc) : "v"(w), "v"(h));
}

// 2-round butterfly: every lane of each 4-group holds the 4-lane sum.
__device__ __forceinline__ float quad_sum(float v) {
    v += __int_as_float(__builtin_amdgcn_update_dpp(0, __float_as_int(v), 0xB1, 0xF, 0xF, true)); // xor1
    v += __int_as_float(__builtin_amdgcn_update_dpp(0, __float_as_int(v), 0x4E, 0xF, 0xF, true)); // xor2
    return v;
}
// 3-round butterfly over 8-lane group (quad-uniform before mirror -> xor4 ok)
__device__ __forceinline__ float grp8_sum(float v) {
    v += __int_as_float(__builtin_amdgcn_update_dpp(0, __float_as_int(v), 0xB1, 0xF, 0xF, true));
    v += __int_as_float(__builtin_amdgcn_update_dpp(0, __float_as_int(v), 0x4E, 0xF, 0xF, true));
    v += __int_as_float(__builtin_amdgcn_update_dpp(0, __float_as_int(v), 0x141, 0xF, 0xF, true));
    return v;
}

__global__
__attribute__((amdgpu_flat_work_group_size(NT, NT), amdgpu_waves_per_eu(4, 4)))
void decoder_rnn_kernel(const float* __restrict__ h0,
                        const float* __restrict__ c0,
                        const float* __restrict__ tonehot,   // (MAXLEN+1, 1, OUT)
                        const void*  __restrict__ tf_raw,    // bool mask, int8 or int32
                        const float* __restrict__ Wih,       // (4H, OUT)
                        const float* __restrict__ Whh,       // (4H, H)
                        const float* __restrict__ bih,
                        const float* __restrict__ bhh,
                        const float* __restrict__ Wout,      // (OUT, H)
                        const float* __restrict__ bout,
                        float* __restrict__ out)
{
    // R21 = R20 + PIN on the weight quads (blocks rematerialization of the
    // per-step Whh reloads that kept VGPR_Count at 60) + tf/tgt prefetch.
    // 16 waves; wave w owns gates [(w>>1)*64,+64) over K-half (w&1)*64.
    // Lane: 8 gates x 8 K = 64 weight floats (16 quads), register-resident.
    __shared__ __align__(16) float h_lds[HID];
    __shared__ __align__(16) float gpart[4][520];    // partial planes, padded
    __shared__ float wih_eff[OUT * 512];             // Wih^T + bias, [x][g]
    __shared__ float WoutL[8][132];                  // row 7 = zeros, padded
    __shared__ float lp[2][8];                       // logit K-half partials
    __shared__ float ring[RINGD][OUT];               // RAW logits
    __shared__ unsigned char tgt8[MAXLEN];
    __shared__ unsigned char tf8[MAXLEN];
    __shared__ int tf_byte_mode;

    const int t     = threadIdx.x;
    const int lane  = t & 63;
    const int wv    = t >> 6;         // 0..15
    const int ksl   = lane & 7;       // K sub-slice (8 wide)
    const int grp   = lane >> 3;      // 8-gate group
    const int b     = blockIdx.x;
    const int kset  = wv & 1;         // K-half
    const int gw    = wv >> 1;        // gate block
    const int gbase = gw * 64 + grp * 8;
    const int kb    = kset * 64 + ksl * 8;

    // ---- persistent W_hh: 8 gates x 8 K = 16 quads (64 VGPR), PINNED ----
    float4v wq[8][2];
    #pragma unroll
    for (int g = 0; g < 8; g++)
        #pragma unroll
        for (int p = 0; p < 2; p++)
            wq[g][p] = *(const float4v*)&Whh[(size_t)(gbase + g) * HID + kb + p * 4];
    #pragma unroll
    for (int g = 0; g < 8; g++)
        #pragma unroll
        for (int p = 0; p < 2; p++)
            asm volatile("" : "+v"(wq[g][p]));   // forbid remat; force residency

    float boutr[OUT];
    #pragma unroll
    for (int j = 0; j < OUT; j++) boutr[j] = bout[j];

    // ---- LDS setup ----
    for (int idx = t; idx < OUT * 512; idx += NT) {
        int x = idx >> 9, g = idx & 511;
        wih_eff[idx] = Wih[g * OUT + x] + bih[g] + bhh[g];
    }
    if (t < HID) WoutL[7][t] = 0.f;                 // zero pad row
    for (int idx = t; idx < OUT * HID; idx += NT)
        WoutL[idx >> 7][idx & 127] = Wout[idx];
    if (t == 0) tf_byte_mode = 0;
    for (int s = t; s < MAXLEN; s += NT) {
        const float* row = tonehot + (size_t)(s + 1) * OUT;
        int idx = 0;
        #pragma unroll
        for (int j = 0; j < OUT; j++) if (row[j] > 0.5f) idx = j;
        tgt8[s] = (unsigned char)idx;
    }
    __syncthreads();
    {   // tf_mask layout detection (int8 bool vs int32) — proven R1-R16
        const unsigned char* tb = (const unsigned char*)tf_raw;
        int mis = 0;
        for (int p = t; p < MAXLEN; p += NT)
            if ((p & 3) && tb[p]) mis = 1;
        if (mis) atomicOr(&tf_byte_mode, 1);
    }
    // ---- state init ----
    float c_reg = 0.f, hv = 0.f;
    if (t < HID) {
        hv    = h0[b * HID + t];
        c_reg = c0[b * HID + t];
        h_lds[t] = hv;
    }
    __syncthreads();
    if (tf_byte_mode) {
        const unsigned char* tb = (const unsigned char*)tf_raw;
        for (int s = t; s < MAXLEN; s += NT) tf8[s] = (tb[s] != 0);
    } else {
        const int* ti = (const int*)tf_raw;
        for (int s = t; s < MAXLEN; s += NT) tf8[s] = (ti[s] != 0);
    }
    __syncthreads();

    float* outlp = out + (size_t)b * MAXLEN * OUT;

    for (int s = 0; s < MAXLEN; s++) {
        // prefetch step-control bytes early (latency hides under FMA block)
        int tfp = 0, tgp = 0;
        if (s > 0) { tfp = tf8[s - 1]; tgp = tgt8[s - 1]; }

        // ---- phase 1: gates matvec (pk_fma) + logit K-halves on waves 0/1 ----
        const float4v h0q = *(const float4v*)&h_lds[kb];
        const float4v h1q = *(const float4v*)&h_lds[kb + 4];
        const float2v hl0 = vlo(h0q), hh0 = vhi(h0q);
        const float2v hl1 = vlo(h1q), hh1 = vhi(h1q);

        float2v acc[8];
        #pragma unroll
        for (int g = 0; g < 8; g++) { float2v z = {0.f, 0.f}; acc[g] = z; }
        #pragma unroll
        for (int g = 0; g < 8; g++) {
            pk_fma(acc[g], vlo(wq[g][0]), hl0);
            pk_fma(acc[g], vhi(wq[g][0]), hh0);
            pk_fma(acc[g], vlo(wq[g][1]), hl1);
            pk_fma(acc[g], vhi(wq[g][1]), hh1);
        }
        float a[8];
        #pragma unroll
        for (int g = 0; g < 8; g++) a[g] = quad_sum(acc[g][0] + acc[g][1]);
        if ((ksl & 3) == 0) {
            const int pl = (kset << 1) | (ksl >> 2);
            float4v g4a, g4b;
            g4a[0] = a[0]; g4a[1] = a[1]; g4a[2] = a[2]; g4a[3] = a[3];
            g4b[0] = a[4]; g4b[1] = a[5]; g4b[2] = a[6]; g4b[3] = a[7];
            *(float4v*)&gpart[pl][gbase]     = g4a;
            *(float4v*)&gpart[pl][gbase + 4] = g4b;
        }
        if (wv < 2) {   // logit row grp over my K-half (row 7 reads zeros)
            const float4v wo0 = *(const float4v*)&WoutL[grp][kb];
            const float4v wo1 = *(const float4v*)&WoutL[grp][kb + 4];
            float2v la = {0.f, 0.f};
            pk_fma(la, vlo(wo0), hl0);
            pk_fma(la, vhi(wo0), hh0);
            pk_fma(la, vlo(wo1), hl1);
            pk_fma(la, vhi(wo1), hh1);
            const float al = grp8_sum(la[0] + la[1]);
            if (ksl == 0 && grp < OUT) lp[wv][grp] = al;
        }
        __syncthreads();   // A: gpart + lp ready; h_lds reads done

        // ---- phase 2a: pointwise (waves 0,1) ----
        if (t < HID) {
            const float ps0 = (gpart[0][t] + gpart[1][t]) + (gpart[2][t] + gpart[3][t]);
            const float ps1 = (gpart[0][128 + t] + gpart[1][128 + t]) + (gpart[2][128 + t] + gpart[3][128 + t]);
            const float ps2 = (gpart[0][256 + t] + gpart[1][256 + t]) + (gpart[2][256 + t] + gpart[3][256 + t]);
            const float ps3 = (gpart[0][384 + t] + gpart[1][384 + t]) + (gpart[2][384 + t] + gpart[3][384 + t]);
            int xsel = OUT - 1;
            if (s > 0) {
                if (t < OUT) ring[(s - 1) & (RINGD - 1)][t] = lp[0][t] + lp[1][t];
                if (tfp) {
                    xsel = tgp;
                } else {
                    float lg[OUT];
                    #pragma unroll
                    for (int j = 0; j < OUT; j++)
                        lg[j] = lp[0][j] + lp[1][j] + boutr[j];
                    float bv = lg[0]; int bi = 0;
                    #pragma unroll
                    for (int j = 1; j < OUT; j++) if (lg[j] > bv) { bv = lg[j]; bi = j; }
                    xsel = bi;
                }
            }
            const int xo = xsel * 512;
            const float ri = ps0 + wih_eff[xo + t];
            const float rf = ps1 + wih_eff[xo + 128 + t];
            const float rg = ps2 + wih_eff[xo + 256 + t];
            const float ro = ps3 + wih_eff[xo + 384 + t];
            const float cn = sigm_(rf) * c_reg + sigm_(ri) * tanh_(rg);
            c_reg = cn;
            hv = sigm_(ro) * tanh_(cn);
            h_lds[t] = hv;
        } else if (t >= 128 && t < 384 && (s & 255) == 1 && s > 256) {
            // ---- phase 2b: deferred log-softmax flush (waves 2-5) ----
            const int step = (s - 257) + (t - 128);      // slot-disjoint from (s-1)
            const int slot = step & (RINGD - 1);
            float v[OUT];
            #pragma unroll
            for (int j = 0; j < OUT; j++) v[j] = ring[slot][j] + boutr[j];
            float mx = v[0];
            #pragma unroll
            for (int j = 1; j < OUT; j++) mx = fmaxf(mx, v[j]);
            float sum = 0.f;
            #pragma unroll
            for (int j = 0; j < OUT; j++) sum += __expf(v[j] - mx);
            const float lse = mx + __logf(sum);
            float* dst = outlp + (size_t)step * OUT;
            #pragma unroll
            for (int j = 0; j < OUT; j++) dst[j] = v[j] - lse;
        }
        __syncthreads();   // C: h(s+1) visible to all waves
    }

    // ---- epilogue: raw logits for step 2047 from final h ----
    if (wv < 2) {
        const float4v h0q = *(const float4v*)&h_lds[kb];
        const float4v h1q = *(const float4v*)&h_lds[kb + 4];
        const float4v wo0 = *(const float4v*)&WoutL[grp][kb];
        const float4v wo1 = *(const float4v*)&WoutL[grp][kb + 4];
        float2v la = {0.f, 0.f};
        pk_fma(la, vlo(wo0), vlo(h0q));
        pk_fma(la, vhi(wo0), vhi(h0q));
        pk_fma(la, vlo(wo1), vlo(h1q));
        pk_fma(la, vhi(wo1), vhi(h1q));
        const float al = grp8_sum(la[0] + la[1]);
        if (ksl == 0 && grp < OUT) lp[wv][grp] = al;
    }
    __syncthreads();
    if (t < OUT)
        ring[(MAXLEN - 1) & (RINGD - 1)][t] = lp[0][t] + lp[1][t];
    __syncthreads();
    if (t < 256) {   // final flush: steps 1792..2047
        const int step = (MAXLEN - 256) + t;
        const int slot = step & (RINGD - 1);
        float v[OUT];
        #pragma unroll
        for (int j = 0; j < OUT; j++) v[j] = ring[slot][j] + boutr[j];
        float mx = v[0];
        #pragma unroll
        for (int j = 1; j < OUT; j++) mx = fmaxf(mx, v[j]);
        float sum = 0.f;
        #pragma unroll
        for (int j = 0; j < OUT; j++) sum += __expf(v[j] - mx);
        const float lse = mx + __logf(sum);
        float* dst = outlp + (size_t)step * OUT;
        #pragma unroll
        for (int j = 0; j < OUT; j++) dst[j] = v[j] - lse;
    }
    if (t < HID) {
        out[OFF_STATE + b * HID + t] = hv;                        // hT
        out[OFF_STATE + BATCH * HID + b * HID + t] = c_reg;       // cT
    }
}

extern "C" void kernel_launch(void* const* d_in, const int* in_sizes, int n_in,
                              void* d_out, int out_size, void* d_ws, size_t ws_size,
                              hipStream_t stream) {
    const float* h0    = (const float*)d_in[0];
    const float* c0    = (const float*)d_in[1];
    const float* toh   = (const float*)d_in[2];
    const void*  tfm   = (const void*) d_in[3];
    const float* Wih   = (const float*)d_in[4];
    const float* Whh   = (const float*)d_in[5];
    const float* bih   = (const float*)d_in[6];
    const float* bhh   = (const float*)d_in[7];
    const float* Wout  = (const float*)d_in[8];
    const float* bout  = (const float*)d_in[9];
    float* out = (float*)d_out;

    decoder_rnn_kernel<<<dim3(BATCH), dim3(NT), 0, stream>>>(
        h0, c0, toh, tfm, Wih, Whh, bih, bhh, Wout, bout, out);
}

// Round 6
// 2203.464 us; speedup vs baseline: 1.1996x; 1.0438x over previous
//
#include <hip/hip_runtime.h>
#include <math.h>

#define BATCH 10
#define HID 128
#define OUT 7
#define MAXLEN 2048
#define NG 512
#define NT 512
#define RINGD 512
#define OFF_STATE ((size_t)BATCH * MAXLEN * OUT)

typedef float float2v __attribute__((ext_vector_type(2)));
typedef float float4v __attribute__((ext_vector_type(4)));

__device__ __forceinline__ float sigm_(float x) { return 1.0f / (1.0f + __expf(-x)); }
__device__ __forceinline__ float tanh_(float x) { return 1.0f - 2.0f / (1.0f + __expf(2.0f * x)); }

__device__ __forceinline__ float2v vlo(float4v v) { return __builtin_shufflevector(v, v, 0, 1); }
__device__ __forceinline__ float2v vhi(float4v v) { return __builtin_shufflevector(v, v, 2, 3); }

// guaranteed packed fp32 FMA (2 MACs/instr)
__device__ __forceinline__ void pk_fma(float2v& acc, float2v w, float2v h) {
    asm("v_pk_fma_f32 %0, %1, %2, %0" : "+v"(acc) : "v"(w), "v"(h));
}

// 3-round butterfly over 8-lane group: xor1, xor2, then row_half_mirror
// (= xor7, valid as xor4 because quads are uniform after rounds 1-2).
__device__ __forceinline__ float grp8_sum(float v) {
    v += __int_as_float(__builtin_amdgcn_update_dpp(0, __float_as_int(v), 0xB1, 0xF, 0xF, true));
    v += __int_as_float(__builtin_amdgcn_update_dpp(0, __float_as_int(v), 0x4E, 0xF, 0xF, true));
    v += __int_as_float(__builtin_amdgcn_update_dpp(0, __float_as_int(v), 0x141, 0xF, 0xF, true));
    return v;
}

__global__
__attribute__((amdgpu_flat_work_group_size(NT, NT), amdgpu_waves_per_eu(2, 2)))
void decoder_rnn_kernel(const float* __restrict__ h0,
                        const float* __restrict__ c0,
                        const float* __restrict__ tonehot,   // (MAXLEN+1, 1, OUT)
                        const void*  __restrict__ tf_raw,    // bool mask, int8 or int32
                        const float* __restrict__ Wih,       // (4H, OUT)
                        const float* __restrict__ Whh,       // (4H, H)
                        const float* __restrict__ bih,
                        const float* __restrict__ bhh,
                        const float* __restrict__ Wout,      // (OUT, H)
                        const float* __restrict__ bout,
                        float* __restrict__ out)
{
    // R22 = R18 geometry + laundered weight pointers (kills invariant-load
    // remat) + pinned quads (NT=512 -> 256-VGPR budget, demand ~215) +
    // tf-step wih prefetch. 8 waves; wave w owns gates [w*64,+64) full-K;
    // lane (grp=lane>>3, ksl=lane&7): 8 gates x 16 K = 128 weight floats.
    __shared__ __align__(16) float h_lds[HID];
    __shared__ __align__(16) float gates_lds[NG];
    __shared__ float wih_eff[OUT * NG];              // Wih^T + bias, [x][g]
    __shared__ float ring[RINGD][OUT];               // RAW logits (bout at flush)
    __shared__ unsigned char tgt8[MAXLEN];
    __shared__ unsigned char tf8[MAXLEN];
    __shared__ int tf_byte_mode;

    const int t     = threadIdx.x;
    const int lane  = t & 63;
    const int wv    = t >> 6;         // 0..7
    const int ksl   = lane & 7;       // K sub-slice (16 wide, strided by 4)
    const int grp   = lane >> 3;      // 8-gate group
    const int b     = blockIdx.x;
    const int gbase = wv * 64 + grp * 8;

    // ---- launder weight pointers: loads no longer provably invariant ----
    unsigned long long whh_a  = (unsigned long long)Whh;
    unsigned long long wout_a = (unsigned long long)Wout;
    asm volatile("" : "+v"(whh_a), "+v"(wout_a));
    const float* whh_p  = (const float*)whh_a;
    const float* wout_p = (const float*)wout_a;

    // ---- persistent W_hh: 8 gates x 4 quads (128 VGPR), pinned ----
    // k indices c*32 + ksl*4 + [0,4): for fixed c the 8 ksl addresses tile
    // banks 4*ksl..4*ksl+3 -> conflict-free b128 broadcast (proven R18).
    float4v wq[8][4];
    #pragma unroll
    for (int g = 0; g < 8; g++)
        #pragma unroll
        for (int c = 0; c < 4; c++)
            wq[g][c] = *(const float4v*)&whh_p[(size_t)(gbase + g) * HID + c * 32 + ksl * 4];
    #pragma unroll
    for (int g = 0; g < 8; g++)
        #pragma unroll
        for (int c = 0; c < 4; c++)
            asm volatile("" : "+v"(wq[g][c]));

    // logit weights: waves 0/1, lane-group grp -> logit row grp (zeros grp>=7)
    float4v lw[4];
    #pragma unroll
    for (int c = 0; c < 4; c++) { float4v z = {0.f, 0.f, 0.f, 0.f}; lw[c] = z; }
    if (wv < 2 && grp < OUT) {
        #pragma unroll
        for (int c = 0; c < 4; c++)
            lw[c] = *(const float4v*)&wout_p[(size_t)grp * HID + c * 32 + ksl * 4];
    }
    #pragma unroll
    for (int c = 0; c < 4; c++)
        asm volatile("" : "+v"(lw[c]));

    float boutr[OUT];
    #pragma unroll
    for (int j = 0; j < OUT; j++) boutr[j] = bout[j];

    // ---- LDS setup ----
    for (int idx = t; idx < OUT * NG; idx += NT) {
        int x = idx >> 9, g = idx & (NG - 1);
        wih_eff[idx] = Wih[g * OUT + x] + bih[g] + bhh[g];
    }
    if (t == 0) tf_byte_mode = 0;
    for (int s = t; s < MAXLEN; s += NT) {
        const float* row = tonehot + (size_t)(s + 1) * OUT;
        int idx = 0;
        #pragma unroll
        for (int j = 0; j < OUT; j++) if (row[j] > 0.5f) idx = j;
        tgt8[s] = (unsigned char)idx;
    }
    __syncthreads();
    {   // tf_mask layout detection (int8 bool vs int32) — proven R1-R16
        const unsigned char* tb = (const unsigned char*)tf_raw;
        int mis = 0;
        for (int p = t; p < MAXLEN; p += NT)
            if ((p & 3) && tb[p]) mis = 1;
        if (mis) atomicOr(&tf_byte_mode, 1);
    }
    // ---- state init ----
    float c_reg = 0.f, hv = 0.f;
    if (t < HID) {
        hv    = h0[b * HID + t];
        c_reg = c0[b * HID + t];
        h_lds[t] = hv;
    }
    __syncthreads();
    if (tf_byte_mode) {
        const unsigned char* tb = (const unsigned char*)tf_raw;
        for (int s = t; s < MAXLEN; s += NT) tf8[s] = (tb[s] != 0);
    } else {
        const int* ti = (const int*)tf_raw;
        for (int s = t; s < MAXLEN; s += NT) tf8[s] = (ti[s] != 0);
    }
    __syncthreads();

    float* outlp = out + (size_t)b * MAXLEN * OUT;

    for (int s = 0; s < MAXLEN; s++) {
        // step-control bytes (block-uniform), early
        int tfp = 0, tgp = 0;
        if (s > 0) { tfp = tf8[s - 1]; tgp = tgt8[s - 1]; }

        // tf-step wih prefetch (waves 0/1): xsel is known -> hide the LDS
        // latency under the FMA block instead of serializing after argmax
        float wpre0 = 0.f, wpre1 = 0.f, wpre2 = 0.f, wpre3 = 0.f;
        if (t < HID && tfp) {
            const int xo = tgp * NG;
            wpre0 = wih_eff[xo + t];
            wpre1 = wih_eff[xo + 128 + t];
            wpre2 = wih_eff[xo + 256 + t];
            wpre3 = wih_eff[xo + 384 + t];
        }

        // ---- phase 1: packed-fp32 matvec + logits on waves 0/1 ----
        float4v hc[4];
        #pragma unroll
        for (int c = 0; c < 4; c++)
            hc[c] = *(const float4v*)&h_lds[c * 32 + ksl * 4];   // conflict-free

        float2v acc[8];
        #pragma unroll
        for (int g = 0; g < 8; g++) { float2v z = {0.f, 0.f}; acc[g] = z; }
        #pragma unroll
        for (int c = 0; c < 4; c++) {
            const float2v hlo = vlo(hc[c]), hhi = vhi(hc[c]);
            #pragma unroll
            for (int g = 0; g < 8; g++) {
                pk_fma(acc[g], vlo(wq[g][c]), hlo);
                pk_fma(acc[g], vhi(wq[g][c]), hhi);
            }
        }
        float a[8];
        #pragma unroll
        for (int g = 0; g < 8; g++) a[g] = grp8_sum(acc[g][0] + acc[g][1]);

        float al = 0.f;
        if (wv < 2) {
            float2v la = {0.f, 0.f};
            #pragma unroll
            for (int c = 0; c < 4; c++) {
                pk_fma(la, vlo(lw[c]), vlo(hc[c]));
                pk_fma(la, vhi(lw[c]), vhi(hc[c]));
            }
            al = grp8_sum(la[0] + la[1]);    // lane holds raw logit[grp]
        }
        if (ksl == 0) {
            float4v g4a, g4b;
            g4a[0] = a[0]; g4a[1] = a[1]; g4a[2] = a[2]; g4a[3] = a[3];
            g4b[0] = a[4]; g4b[1] = a[5]; g4b[2] = a[6]; g4b[3] = a[7];
            *(float4v*)&gates_lds[gbase]     = g4a;
            *(float4v*)&gates_lds[gbase + 4] = g4b;
        }
        __syncthreads();   // A: gates ready; h_lds reads done

        // ---- phase 2a: pointwise (waves 0,1) ----
        if (t < HID) {
            if (s > 0 && wv == 0 && ksl == 0 && grp < OUT)
                ring[(s - 1) & (RINGD - 1)][grp] = al;   // raw logit
            float w0, w1, w2, w3;
            if (tfp) {
                w0 = wpre0; w1 = wpre1; w2 = wpre2; w3 = wpre3;
            } else {
                int xsel = OUT - 1;
                if (s > 0) {
                    float lg[OUT];
                    #pragma unroll
                    for (int j = 0; j < OUT; j++)
                        lg[j] = __int_as_float(__builtin_amdgcn_readlane(__float_as_int(al), 8 * j)) + boutr[j];
                    float bv = lg[0]; int bi = 0;
                    #pragma unroll
                    for (int j = 1; j < OUT; j++) if (lg[j] > bv) { bv = lg[j]; bi = j; }
                    xsel = bi;
                }
                const int xo = xsel * NG;
                w0 = wih_eff[xo + t];
                w1 = wih_eff[xo + 128 + t];
                w2 = wih_eff[xo + 256 + t];
                w3 = wih_eff[xo + 384 + t];
            }
            const float ri = gates_lds[t]           + w0;
            const float rf = gates_lds[HID + t]     + w1;
            const float rg = gates_lds[2 * HID + t] + w2;
            const float ro = gates_lds[3 * HID + t] + w3;
            const float cn = sigm_(rf) * c_reg + sigm_(ri) * tanh_(rg);
            c_reg = cn;
            hv = sigm_(ro) * tanh_(cn);
            h_lds[t] = hv;
        } else if (t >= 256 && (s & 255) == 1 && s > 256) {
            // ---- phase 2b: deferred log-softmax flush (waves 4-7) ----
            const int step = (s - 257) + (t - 256);      // slot-disjoint from (s-1)
            const int slot = step & (RINGD - 1);
            float v[OUT];
            #pragma unroll
            for (int j = 0; j < OUT; j++) v[j] = ring[slot][j] + boutr[j];
            float mx = v[0];
            #pragma unroll
            for (int j = 1; j < OUT; j++) mx = fmaxf(mx, v[j]);
            float sum = 0.f;
            #pragma unroll
            for (int j = 0; j < OUT; j++) sum += __expf(v[j] - mx);
            const float lse = mx + __logf(sum);
            float* dst = outlp + (size_t)step * OUT;
            #pragma unroll
            for (int j = 0; j < OUT; j++) dst[j] = v[j] - lse;
        }
        __syncthreads();   // C: h(s+1) visible
    }

    // ---- epilogue: raw logits for step 2047 from final h ----
    if (wv < 2) {
        float2v la = {0.f, 0.f};
        #pragma unroll
        for (int c = 0; c < 4; c++) {
            const float4v h4 = *(const float4v*)&h_lds[c * 32 + ksl * 4];
            pk_fma(la, vlo(lw[c]), vlo(h4));
            pk_fma(la, vhi(lw[c]), vhi(h4));
        }
        const float al = grp8_sum(la[0] + la[1]);
        if (wv == 0 && ksl == 0 && grp < OUT)
            ring[(MAXLEN - 1) & (RINGD - 1)][grp] = al;
    }
    __syncthreads();
    if (t < 256) {   // final flush: steps 1792..2047
        const int step = (MAXLEN - 256) + t;
        const int slot = step & (RINGD - 1);
        float v[OUT];
        #pragma unroll
        for (int j = 0; j < OUT; j++) v[j] = ring[slot][j] + boutr[j];
        float mx = v[0];
        #pragma unroll
        for (int j = 1; j < OUT; j++) mx = fmaxf(mx, v[j]);
        float sum = 0.f;
        #pragma unroll
        for (int j = 0; j < OUT; j++) sum += __expf(v[j] - mx);
        const float lse = mx + __logf(sum);
        float* dst = outlp + (size_t)step * OUT;
        #pragma unroll
        for (int j = 0; j < OUT; j++) dst[j] = v[j] - lse;
    }
    if (t < HID) {
        out[OFF_STATE + b * HID + t] = hv;                        // hT
        out[OFF_STATE + BATCH * HID + b * HID + t] = c_reg;       // cT
    }
}

extern "C" void kernel_launch(void* const* d_in, const int* in_sizes, int n_in,
                              void* d_out, int out_size, void* d_ws, size_t ws_size,
                              hipStream_t stream) {
    const float* h0    = (const float*)d_in[0];
    const float* c0    = (const float*)d_in[1];
    const float* toh   = (const float*)d_in[2];
    const void*  tfm   = (const void*) d_in[3];
    const float* Wih   = (const float*)d_in[4];
    const float* Whh   = (const float*)d_in[5];
    const float* bih   = (const float*)d_in[6];
    const float* bhh   = (const float*)d_in[7];
    const float* Wout  = (const float*)d_in[8];
    const float* bout  = (const float*)d_in[9];
    float* out = (float*)d_out;

    decoder_rnn_kernel<<<dim3(BATCH), dim3(NT), 0, stream>>>(
        h0, c0, toh, tfm, Wih, Whh, bih, bhh, Wout, bout, out);
}